// Round 2
// baseline (451.990 us; speedup 1.0000x reference)
//
#include <hip/hip_runtime.h>
#include <hip/hip_bf16.h>
#include <stdint.h>

#define BSZ   8192
#define D_IN  4096
#define D_OUT 4096
#define NM    128   // 8192/64 m-blocks
#define NK    64    // 4096/64 k-blocks

typedef __bf16 bf16x8 __attribute__((ext_vector_type(8)));
typedef float  f32x4  __attribute__((ext_vector_type(4)));
typedef unsigned short ushort_t;

__device__ __forceinline__ ushort_t f2bf(float f) {
  union { __hip_bfloat16 h; ushort_t u; } c;
  c.h = __float2bfloat16(f);
  return c.u;
}

__device__ __forceinline__ bf16x8 ld_frag(const ushort_t* p) {
  union { uint4 u; bf16x8 b; } cv;
  cv.u = *(const uint4*)p;
  return cv.b;
}

__device__ __forceinline__ void glds16(const ushort_t* g, ushort_t* l) {
  __builtin_amdgcn_global_load_lds(
      (const __attribute__((address_space(1))) unsigned int*)g,
      (__attribute__((address_space(3))) unsigned int*)l,
      16, 0, 0);
}

// ---------------------------------------------------------------------------
// Kernel A: per 64x64 block -> fp64 abs-sum -> mask; write x as bf16 only for
// active blocks. (unchanged: isolating GEMM pipeline change; if GEMM drops
// below A/B, next round's top-5 reveals their true durations)
// ---------------------------------------------------------------------------
__global__ __launch_bounds__(256) void mask_cast_kernel(
    const float* __restrict__ x, ushort_t* __restrict__ xb,
    int* __restrict__ mask) {
  const int kblk = blockIdx.x;   // 0..63
  const int mblk = blockIdx.y;   // 0..127
  const int tid  = threadIdx.x;
  const int lane = tid & 63;
  const int wv   = tid >> 6;
  const size_t row0 = (size_t)mblk * 64;
  const int    col0 = kblk * 64;

  float4 v[4];
  double s = 0.0;
#pragma unroll
  for (int i = 0; i < 4; ++i) {
    int j = i * 256 + tid;       // flat float4 index in 64x16 grid
    int r = j >> 4;              // row 0..63
    int c = (j & 15) * 4;        // col 0..60
    v[i] = *(const float4*)(x + (row0 + r) * D_IN + col0 + c);
    s += (double)fabsf(v[i].x) + (double)fabsf(v[i].y) +
         (double)fabsf(v[i].z) + (double)fabsf(v[i].w);
  }

  // wave-level butterfly reduction of the double sum (no barriers)
#pragma unroll
  for (int off = 32; off > 0; off >>= 1) {
    union { double d; int i2[2]; } u;
    u.d = s;
    u.i2[0] = __shfl_xor(u.i2[0], off, 64);
    u.i2[1] = __shfl_xor(u.i2[1], off, 64);
    s += u.d;
  }

  __shared__ double wsum[4];
  __shared__ int mflag;
  if (lane == 0) wsum[wv] = s;
  __syncthreads();
  if (tid == 0) {
    double tot = wsum[0] + wsum[1] + wsum[2] + wsum[3];
    float avg = (float)(tot * (1.0 / 4096.0));
    int m = (avg > 0.8f) ? 1 : 0;
    mflag = m;
    mask[mblk * NK + kblk] = m;
  }
  __syncthreads();

  if (mflag) {
#pragma unroll
    for (int i = 0; i < 4; ++i) {
      int j = i * 256 + tid;
      int r = j >> 4;
      int c = (j & 15) * 4;
      ushort4 o = make_ushort4(f2bf(v[i].x), f2bf(v[i].y),
                               f2bf(v[i].z), f2bf(v[i].w));
      *(ushort4*)(xb + (row0 + r) * D_IN + col0 + c) = o;
    }
  }
}

// ---------------------------------------------------------------------------
// Kernel B: w[k][n] fp32 -> wT[n][k] bf16 (LDS 64x64 tile transpose).
// (unchanged this round)
// ---------------------------------------------------------------------------
__global__ __launch_bounds__(256) void wcast_transpose_kernel(
    const float* __restrict__ w, ushort_t* __restrict__ wT) {
  const int ntile = blockIdx.x;  // 0..63
  const int ktile = blockIdx.y;  // 0..63
  const int tid   = threadIdx.x;
  const int k0 = ktile * 64, n0 = ntile * 64;

  __shared__ ushort_t t[64][65];  // +1 pad breaks transpose bank conflicts

#pragma unroll
  for (int i = 0; i < 4; ++i) {
    int j = i * 256 + tid;
    int r = j >> 4;              // k within tile
    int c = (j & 15) * 4;        // n within tile
    float4 v = *(const float4*)(w + (size_t)(k0 + r) * D_OUT + n0 + c);
    t[r][c + 0] = f2bf(v.x);
    t[r][c + 1] = f2bf(v.y);
    t[r][c + 2] = f2bf(v.z);
    t[r][c + 3] = f2bf(v.w);
  }
  __syncthreads();
#pragma unroll
  for (int i = 0; i < 4; ++i) {
    int j = i * 256 + tid;
    int r = j >> 4;              // n within tile
    int c = (j & 15) * 4;        // k within tile
    ushort4 o = make_ushort4(t[c + 0][r], t[c + 1][r], t[c + 2][r], t[c + 3][r]);
    *(ushort4*)(wT + (size_t)(n0 + r) * D_IN + k0 + c) = o;
  }
}

// ---------------------------------------------------------------------------
// Kernel C: block-sparse bf16 MFMA GEMM.  NEW THIS ROUND: double-buffered
// LDS prefetch with COUNTED vmcnt (T3-minimum / 2-phase recipe).
//
// Geometry unchanged from R1: BM=128 (two 64-row mask blocks, union k-list
// with per-row act bits), BN=256, BK=64, 512 thr = 8 waves, wave (mi,nj)
// owns a 64x64 output subtile.
//
// Pipeline per union-k iter:
//   1. issue glds for tile ki+1 into buf[cur^1]   (4 or 6 loads, per-wave)
//   2. s_waitcnt vmcnt(c_next)  -> tile ki's LDS writes (issued last iter)
//      are complete; the just-issued c_next loads stay IN FLIGHT across the
//      barrier (this replaces __syncthreads' vmcnt(0) full drain)
//   3. s_barrier                -> tile ki visible to all waves
//   4. ds_read frags + 32 MFMA  (skipped wave-uniformly if my m-block
//      inactive; compiler's lgkmcnt covers read->MFMA)
//   5. s_barrier                -> all reads of buf[cur] done; next iter may
//      overwrite it.  cur ^= 1.
// Loads get a full iteration (~350+ cyc of ds_read+MFMA) to land instead of
// being drained cold.  Cost: 96 KB LDS -> 1 WG/CU (8 waves); trading
// cross-WG TLP for in-wave pipelining per the 2ph/8ph family.
//
// LDS XOR swizzle unchanged (slot s of row r holds global chunk s^(r&7));
// SQ_LDS_BANK_CONFLICT == 0 in R0/R1.
// ---------------------------------------------------------------------------
__global__ __launch_bounds__(512) void bsp_gemm_kernel(
    const ushort_t* __restrict__ xb, const ushort_t* __restrict__ wT,
    const int* __restrict__ mask, float* __restrict__ out) {
  const int ntile = blockIdx.x;  // 0..15
  const int mpair = blockIdx.y;  // 0..63  (m-blocks 2*mpair, 2*mpair+1)
  const int tid   = threadIdx.x;
  const int lane  = tid & 63;
  const int wv    = tid >> 6;    // wave 0..7
  const int mi    = wv >> 2;     // row-block within pair: 0..1
  const int nj    = wv & 3;      // n-chunk: 0..3
  const int m0 = mpair * 128;
  const int n0 = ntile * 256;

  __shared__ ushort_t As[2][128 * 64];   // 2 x 16 KB
  __shared__ ushort_t Bs[2][256 * 64];   // 2 x 32 KB  (total 96 KB)
  __shared__ int nact;
  __shared__ unsigned char klist[64];

  // build union active-k list with per-row bits, parallel over wave 0
  if (tid < 64) {
    const int* mrow = mask + (size_t)(mpair * 2) * NK;
    int a0 = (mrow[tid] != 0) ? 1 : 0;
    int a1 = (mrow[NK + tid] != 0) ? 1 : 0;
    unsigned long long u = __ballot(a0 | a1);
    if (a0 | a1) {
      int pos = __popcll(u & ((1ull << tid) - 1ull));
      klist[pos] = (unsigned char)(tid | (a0 << 6) | (a1 << 7));
    }
    if (tid == 0) nact = (int)__popcll(u);
  }
  __syncthreads();
  const int na = nact;

  f32x4 acc[4][4] = {};

  const int lr  = lane >> 3;                       // 0..7 row within 8-row group
  const int lcs = ((lane & 7) ^ (lane >> 3)) * 8;  // swizzled global chunk (ushorts)
  const int q   = lane >> 4;                       // quad 0..3
  const int l15 = lane & 15;
  const int sx  = l15 & 7;                         // row-phase for readback swizzle

  // issue staging loads for klist[ki] into buffer `buf`; returns per-wave
  // outstanding-load count (4 = B only, 6 = B + my A rows)
  auto stage = [&](int ki, int buf) -> int {
    const int e  = klist[ki];
    const int k0 = (e & 63) * 64;
#pragma unroll
    for (int t = 0; t < 4; ++t) {
      int rb = wv * 32 + t * 8;
      glds16(wT + (size_t)(n0 + rb + lr) * D_IN + k0 + lcs, &Bs[buf][rb * 64]);
    }
    if ((e >> (6 + mi)) & 1) {
#pragma unroll
      for (int t = 0; t < 2; ++t) {
        int rb = wv * 16 + t * 8;
        glds16(xb + (size_t)(m0 + rb + lr) * D_IN + k0 + lcs, &As[buf][rb * 64]);
      }
      return 6;
    }
    return 4;
  };

  int cur = 0;
  if (na > 0) stage(0, 0);

  for (int ki = 0; ki < na; ++ki) {
    // 1. prefetch next tile into the other buffer
    int c_next = 0;
    if (ki + 1 < na) c_next = stage(ki + 1, cur ^ 1);

    // 2. counted wait: all loads OLDER than the c_next just issued (= tile
    //    ki, issued last iter / prologue) are complete; prefetch stays in
    //    flight across the barrier.  c_next is wave-uniform.
    if (c_next == 6)      asm volatile("s_waitcnt vmcnt(6)" ::: "memory");
    else if (c_next == 4) asm volatile("s_waitcnt vmcnt(4)" ::: "memory");
    else                  asm volatile("s_waitcnt vmcnt(0)" ::: "memory");

    // 3. tile ki now visible to every wave
    __builtin_amdgcn_s_barrier();
    asm volatile("" ::: "memory");

    // 4. compute (wave-uniform skip if my m-block inactive this k)
    const int e = klist[ki];
    if ((e >> (6 + mi)) & 1) {
#pragma unroll
      for (int c = 0; c < 2; ++c) {
        const int sw = ((c * 4 + q) ^ sx) * 8;   // swizzled chunk offset (ushorts)
        bf16x8 a[4], b[4];
#pragma unroll
        for (int i = 0; i < 4; ++i)
          a[i] = ld_frag(&As[cur][(mi * 64 + i * 16 + l15) * 64 + sw]);
#pragma unroll
        for (int j = 0; j < 4; ++j)
          b[j] = ld_frag(&Bs[cur][(nj * 64 + j * 16 + l15) * 64 + sw]);
#pragma unroll
        for (int i = 0; i < 4; ++i)
#pragma unroll
          for (int j = 0; j < 4; ++j)
            acc[i][j] = __builtin_amdgcn_mfma_f32_16x16x32_bf16(
                a[i], b[j], acc[i][j], 0, 0, 0);
      }
    }

    // 5. everyone done reading buf[cur]; next iter may overwrite it
    asm volatile("" ::: "memory");
    __builtin_amdgcn_s_barrier();
    cur ^= 1;
  }

  // epilogue: C/D layout col=lane&15, row=quad*4+reg
#pragma unroll
  for (int i = 0; i < 4; ++i) {
#pragma unroll
    for (int j = 0; j < 4; ++j) {
#pragma unroll
      for (int r = 0; r < 4; ++r) {
        int row = m0 + mi * 64 + i * 16 + q * 4 + r;
        int col = n0 + nj * 64 + j * 16 + l15;
        out[(size_t)row * D_OUT + col] = acc[i][j][r];
      }
    }
  }
}

// ---------------------------------------------------------------------------
extern "C" void kernel_launch(void* const* d_in, const int* in_sizes, int n_in,
                              void* d_out, int out_size, void* d_ws, size_t ws_size,
                              hipStream_t stream) {
  const float* x = (const float*)d_in[0];
  const float* w = (const float*)d_in[1];

  // workspace layout: x_bf16 (64 MB) | wT_bf16 (32 MB) | mask (32 KB)
  ushort_t* xb  = (ushort_t*)d_ws;
  ushort_t* wT  = (ushort_t*)((char*)d_ws + (size_t)BSZ * D_IN * 2);
  int*      msk = (int*)((char*)d_ws + (size_t)BSZ * D_IN * 2 + (size_t)D_IN * D_OUT * 2);
  float*    out = (float*)d_out;

  hipLaunchKernelGGL(mask_cast_kernel, dim3(NK, NM), dim3(256), 0, stream,
                     x, xb, msk);
  hipLaunchKernelGGL(wcast_transpose_kernel, dim3(64, 64), dim3(256), 0, stream,
                     w, wT);
  hipLaunchKernelGGL(bsp_gemm_kernel, dim3(D_OUT / 256, NM / 2), dim3(512), 0, stream,
                     xb, wT, msk, out);
}

// Round 3
// 420.195 us; speedup vs baseline: 1.0757x; 1.0757x over previous
//
#include <hip/hip_runtime.h>
#include <hip/hip_bf16.h>
#include <stdint.h>

#define BSZ   8192
#define D_IN  4096
#define D_OUT 4096
#define NM    128   // 8192/64 m-blocks
#define NK    64    // 4096/64 k-blocks

typedef __bf16 bf16x8 __attribute__((ext_vector_type(8)));
typedef float  f32x4  __attribute__((ext_vector_type(4)));
typedef unsigned short ushort_t;

__device__ __forceinline__ ushort_t f2bf(float f) {
  union { __hip_bfloat16 h; ushort_t u; } c;
  c.h = __float2bfloat16(f);
  return c.u;
}

__device__ __forceinline__ bf16x8 ld_frag(const ushort_t* p) {
  union { uint4 u; bf16x8 b; } cv;
  cv.u = *(const uint4*)p;
  return cv.b;
}

__device__ __forceinline__ void glds16(const ushort_t* g, ushort_t* l) {
  __builtin_amdgcn_global_load_lds(
      (const __attribute__((address_space(1))) unsigned int*)g,
      (__attribute__((address_space(3))) unsigned int*)l,
      16, 0, 0);
}

// ---------------------------------------------------------------------------
// FUSED prep kernel (R3): kernels A (mask+cast) and B (w transpose+cast) were
// independent but serialized on the stream; non-GEMM time has been a constant
// 241.5 us across R0-R2 while their combined memory roofline is ~40 us.
// Fusing them into one grid with interleaved block assignment (2 A : 1 B per
// triple of blockIdx) overlaps their memory streams and removes one
// kernel-boundary drain.  Math is bit-identical to R0-R2 (fp64 block sums).
//
// Grid: 12288 WGs x 256 thr.  rem = bid%3: rem<2 -> A-block id 2*(bid/3)+rem
// (kblk = id&63, mblk = id>>6); rem==2 -> B-tile id bid/3 (ntile = id&63,
// ktile = id>>6).  Branch is workgroup-uniform.
// ---------------------------------------------------------------------------
__global__ __launch_bounds__(256) void prep_kernel(
    const float* __restrict__ x, ushort_t* __restrict__ xb,
    int* __restrict__ mask,
    const float* __restrict__ w, ushort_t* __restrict__ wT) {
  const int bid = blockIdx.x;
  const int tid = threadIdx.x;
  const int triple = bid / 3;
  const int rem    = bid - triple * 3;

  __shared__ ushort_t t[64][65];   // B-path transpose tile (+1 pad)
  __shared__ double   wsum[4];     // A-path wave sums
  __shared__ int      mflag;

  if (rem < 2) {
    // ---- A-work: per 64x64 block -> fp64 abs-sum -> mask; cast active blocks
    const int id   = triple * 2 + rem;      // 0..8191
    const int kblk = id & 63;
    const int mblk = id >> 6;
    const int lane = tid & 63;
    const int wv   = tid >> 6;
    const size_t row0 = (size_t)mblk * 64;
    const int    col0 = kblk * 64;

    float4 v[4];
    double s = 0.0;
#pragma unroll
    for (int i = 0; i < 4; ++i) {
      int j = i * 256 + tid;       // flat float4 index in 64x16 grid
      int r = j >> 4;              // row 0..63
      int c = (j & 15) * 4;        // col 0..60
      v[i] = *(const float4*)(x + (row0 + r) * D_IN + col0 + c);
      s += (double)fabsf(v[i].x) + (double)fabsf(v[i].y) +
           (double)fabsf(v[i].z) + (double)fabsf(v[i].w);
    }

    // wave-level butterfly reduction of the double sum (no barriers)
#pragma unroll
    for (int off = 32; off > 0; off >>= 1) {
      union { double d; int i2[2]; } u;
      u.d = s;
      u.i2[0] = __shfl_xor(u.i2[0], off, 64);
      u.i2[1] = __shfl_xor(u.i2[1], off, 64);
      s += u.d;
    }

    if (lane == 0) wsum[wv] = s;
    __syncthreads();
    if (tid == 0) {
      double tot = wsum[0] + wsum[1] + wsum[2] + wsum[3];
      float avg = (float)(tot * (1.0 / 4096.0));
      int m = (avg > 0.8f) ? 1 : 0;
      mflag = m;
      mask[mblk * NK + kblk] = m;
    }
    __syncthreads();

    if (mflag) {
#pragma unroll
      for (int i = 0; i < 4; ++i) {
        int j = i * 256 + tid;
        int r = j >> 4;
        int c = (j & 15) * 4;
        ushort4 o = make_ushort4(f2bf(v[i].x), f2bf(v[i].y),
                                 f2bf(v[i].z), f2bf(v[i].w));
        *(ushort4*)(xb + (row0 + r) * D_IN + col0 + c) = o;
      }
    }
  } else {
    // ---- B-work: w[k][n] fp32 -> wT[n][k] bf16 (LDS 64x64 tile transpose)
    const int id    = triple;               // 0..4095
    const int ntile = id & 63;
    const int ktile = id >> 6;
    const int k0 = ktile * 64, n0 = ntile * 64;

#pragma unroll
    for (int i = 0; i < 4; ++i) {
      int j = i * 256 + tid;
      int r = j >> 4;              // k within tile
      int c = (j & 15) * 4;        // n within tile
      float4 v = *(const float4*)(w + (size_t)(k0 + r) * D_OUT + n0 + c);
      t[r][c + 0] = f2bf(v.x);
      t[r][c + 1] = f2bf(v.y);
      t[r][c + 2] = f2bf(v.z);
      t[r][c + 3] = f2bf(v.w);
    }
    __syncthreads();
#pragma unroll
    for (int i = 0; i < 4; ++i) {
      int j = i * 256 + tid;
      int r = j >> 4;              // n within tile
      int c = (j & 15) * 4;        // k within tile
      ushort4 o = make_ushort4(t[c + 0][r], t[c + 1][r],
                               t[c + 2][r], t[c + 3][r]);
      *(ushort4*)(wT + (size_t)(n0 + r) * D_IN + k0 + c) = o;
    }
  }
}

// ---------------------------------------------------------------------------
// Kernel C: block-sparse bf16 MFMA GEMM — REVERTED to the R1 structure (best
// measured: 179 us).  R2's counted-vmcnt double-buffer regressed (210 us):
// 96 KB LDS -> 1 WG/CU lost 3x WG-level TLP, which outweighed the 1-deep
// prefetch in a 2-barrier skeleton.  Next GEMM move, if needed, is the full
// 8-phase interleave, not a half-measure.
//
// BM=128 (two 64-row mask blocks, union k-list with per-row act bits),
// BN=256, BK=64, 512 thr = 8 waves; wave (mi=wv>>2, nj=wv&3) owns a 64x64
// output subtile.  B staged once per union-k, shared by both row-blocks.
// LDS XOR swizzle: slot s of row r holds global chunk s^(r&7); fragment
// reads address chunk (c*4+q)^(row&7) -> conflict-free (0 in R0-R2).
// ---------------------------------------------------------------------------
__global__ __launch_bounds__(512) void bsp_gemm_kernel(
    const ushort_t* __restrict__ xb, const ushort_t* __restrict__ wT,
    const int* __restrict__ mask, float* __restrict__ out) {
  const int ntile = blockIdx.x;  // 0..15
  const int mpair = blockIdx.y;  // 0..63  (m-blocks 2*mpair, 2*mpair+1)
  const int tid   = threadIdx.x;
  const int lane  = tid & 63;
  const int wv    = tid >> 6;    // wave 0..7
  const int mi    = wv >> 2;     // row-block within pair: 0..1
  const int nj    = wv & 3;      // n-chunk: 0..3
  const int m0 = mpair * 128;
  const int n0 = ntile * 256;

  __shared__ ushort_t As[128 * 64];   // [m][k-chunk swizzled] 16 KB
  __shared__ ushort_t Bs[256 * 64];   // [n][k-chunk swizzled] 32 KB
  __shared__ int nact;
  __shared__ unsigned char klist[64];

  // build union active-k list with per-row bits, parallel over wave 0
  if (tid < 64) {
    const int* mrow = mask + (size_t)(mpair * 2) * NK;
    int a0 = (mrow[tid] != 0) ? 1 : 0;
    int a1 = (mrow[NK + tid] != 0) ? 1 : 0;
    unsigned long long u = __ballot(a0 | a1);
    if (a0 | a1) {
      int pos = __popcll(u & ((1ull << tid) - 1ull));
      klist[pos] = (unsigned char)(tid | (a0 << 6) | (a1 << 7));
    }
    if (tid == 0) nact = (int)__popcll(u);
  }
  __syncthreads();
  const int na = nact;

  f32x4 acc[4][4] = {};

  const int lr  = lane >> 3;                       // 0..7 row within 8-row group
  const int lcs = ((lane & 7) ^ (lane >> 3)) * 8;  // swizzled global chunk (ushorts)
  const int q   = lane >> 4;                       // quad 0..3
  const int l15 = lane & 15;
  const int sx  = l15 & 7;                         // row-phase for readback swizzle

  for (int ki = 0; ki < na; ++ki) {
    const int e   = klist[ki];
    const int kb  = e & 63;
    const int k0  = kb * 64;
    const int act = (e >> (6 + mi)) & 1;   // my row-block active this k?

    // stage A rows for MY row-block only if active: waves 0-3 cover rows
    // 0..63 (block 0), waves 4-7 rows 64..127 (block 1); 2 glds/wave.
    if (act) {
#pragma unroll
      for (int t = 0; t < 2; ++t) {
        int rb = wv * 16 + t * 8;
        glds16(xb + (size_t)(m0 + rb + lr) * D_IN + k0 + lcs, &As[rb * 64]);
      }
    }
    // stage B: 256x64 bf16 shared by both row-blocks, 4 glds/wave
#pragma unroll
    for (int t = 0; t < 4; ++t) {
      int rb = wv * 32 + t * 8;
      glds16(wT + (size_t)(n0 + rb + lr) * D_IN + k0 + lcs, &Bs[rb * 64]);
    }
    __syncthreads();

    if (act) {
#pragma unroll
      for (int c = 0; c < 2; ++c) {
        const int sw = ((c * 4 + q) ^ sx) * 8;   // swizzled chunk offset (ushorts)
        bf16x8 a[4], b[4];
#pragma unroll
        for (int i = 0; i < 4; ++i)
          a[i] = ld_frag(&As[(mi * 64 + i * 16 + l15) * 64 + sw]);
#pragma unroll
        for (int j = 0; j < 4; ++j)
          b[j] = ld_frag(&Bs[(nj * 64 + j * 16 + l15) * 64 + sw]);
#pragma unroll
        for (int i = 0; i < 4; ++i)
#pragma unroll
          for (int j = 0; j < 4; ++j)
            acc[i][j] = __builtin_amdgcn_mfma_f32_16x16x32_bf16(
                a[i], b[j], acc[i][j], 0, 0, 0);
      }
    }
    __syncthreads();
  }

  // epilogue: C/D layout col=lane&15, row=quad*4+reg
#pragma unroll
  for (int i = 0; i < 4; ++i) {
#pragma unroll
    for (int j = 0; j < 4; ++j) {
#pragma unroll
      for (int r = 0; r < 4; ++r) {
        int row = m0 + mi * 64 + i * 16 + q * 4 + r;
        int col = n0 + nj * 64 + j * 16 + l15;
        out[(size_t)row * D_OUT + col] = acc[i][j][r];
      }
    }
  }
}

// ---------------------------------------------------------------------------
extern "C" void kernel_launch(void* const* d_in, const int* in_sizes, int n_in,
                              void* d_out, int out_size, void* d_ws, size_t ws_size,
                              hipStream_t stream) {
  const float* x = (const float*)d_in[0];
  const float* w = (const float*)d_in[1];

  // workspace layout: x_bf16 (64 MB) | wT_bf16 (32 MB) | mask (32 KB)
  ushort_t* xb  = (ushort_t*)d_ws;
  ushort_t* wT  = (ushort_t*)((char*)d_ws + (size_t)BSZ * D_IN * 2);
  int*      msk = (int*)((char*)d_ws + (size_t)BSZ * D_IN * 2 + (size_t)D_IN * D_OUT * 2);
  float*    out = (float*)d_out;

  // fused A+B prep: 8192 mask/cast blocks + 4096 transpose tiles,
  // interleaved 2:1 so both memory streams overlap on the device
  hipLaunchKernelGGL(prep_kernel, dim3(12288), dim3(256), 0, stream,
                     x, xb, msk, w, wT);
  hipLaunchKernelGGL(bsp_gemm_kernel, dim3(D_OUT / 256, NM / 2), dim3(512), 0, stream,
                     xb, wT, msk, out);
}